// Round 6
// baseline (124.176 us; speedup 1.0000x reference)
//
#include <hip/hip_runtime.h>
#include <math.h>

#define BB 8
#define NN 512
#define FF 32
#define HH 64
#define NEG_BIG (-1.0e30f)

__device__ __forceinline__ float lane_bcast(float v, int l) {
    return __int_as_float(__builtin_amdgcn_readlane(__float_as_int(v), l));
}

// ---------------------------------------------------------------------------
// encode: h = relu(x@W_enc+b); zi = h@W_e1[:H]+b_e1 (folded); zj = h@W_e1[H:]
// grid 1024 x 256: block = 4 rows, wave qu owns row, lane hh owns column.
// ---------------------------------------------------------------------------
__global__ __launch_bounds__(256) void encode_kernel(
    const float* __restrict__ x, const float* __restrict__ W_enc,
    const float* __restrict__ b_enc, const float* __restrict__ W_e1,
    const float* __restrict__ b_e1,
    float* __restrict__ h, float* __restrict__ zi, float* __restrict__ zj)
{
    const int t = threadIdx.x;
    const int hh = t & 63;
    const int qu = __builtin_amdgcn_readfirstlane(t >> 6);
    const int gR = blockIdx.x * 4 + qu;           // 0..B*N-1

    const float* xrow = x + gR * FF;              // wave-uniform -> s_load
    float acc = b_enc[hh];
#pragma unroll
    for (int k = 0; k < FF; ++k)
        acc = fmaf(xrow[k], W_enc[k * HH + hh], acc);
    const float hval = fmaxf(acc, 0.f);
    h[gR * HH + hh] = hval;

    float z1 = b_e1[hh], z2 = 0.f;
#pragma unroll 8
    for (int k = 0; k < HH; ++k) {
        const float hk = lane_bcast(hval, k);
        z1 = fmaf(hk, W_e1[k * HH + hh], z1);
        z2 = fmaf(hk, W_e1[(HH + k) * HH + hh], z2);
    }
    zi[gR * HH + hh] = z1;
    zj[gR * HH + hh] = z2;
}

// ---------------------------------------------------------------------------
// adj: logits[i,j] = sum_k relu(zi[i,k]+zj[j,k])*W_e2[k]+b_e2, diag -inf,
// softmax over j.  grid 1024 x 256: block = (b, 4 rows); wave qu owns
// j-quarter, lane tj handles j0=128qu+tj, j1=j0+64 for all 4 rows.
// zjs[512][17]: lane stride 17 -> conflict-free.
// ---------------------------------------------------------------------------
__global__ __launch_bounds__(256) void adj_kernel(
    const float* __restrict__ zi, const float* __restrict__ zj,
    const float* __restrict__ W_e2, const float* __restrict__ b_e2,
    float* __restrict__ adj)
{
    const int b = blockIdx.x >> 7;
    const int i0 = (blockIdx.x & 127) << 2;
    const int t = threadIdx.x;
    const int qu = __builtin_amdgcn_readfirstlane(t >> 6);
    const int tj = t & 63;
    const int j0 = (qu << 7) + tj;
    const int j1 = j0 + 64;

    __shared__ float zjs[NN][17];
    __shared__ float red[4][8];

    const float be2 = b_e2[0];
    float acc0[4], acc1[4];
#pragma unroll
    for (int r = 0; r < 4; ++r) { acc0[r] = be2; acc1[r] = be2; }

    const float* zib = zi + (b * NN + i0) * HH;   // wave-uniform -> s_load

    for (int kp = 0; kp < 4; ++kp) {
        __syncthreads();
        for (int idx = t; idx < NN * 16; idx += 256) {
            const int row = idx >> 4, c = idx & 15;
            zjs[row][c] = zj[(b * NN + row) * HH + (kp << 4) + c];
        }
        __syncthreads();
#pragma unroll
        for (int c = 0; c < 16; ++c) {
            const int k = (kp << 4) + c;
            const float w = W_e2[k];
            const float zj0 = zjs[j0][c];
            const float zj1 = zjs[j1][c];
#pragma unroll
            for (int r = 0; r < 4; ++r) {
                const float zv = zib[r * HH + k];
                acc0[r] = fmaf(fmaxf(zv + zj0, 0.f), w, acc0[r]);
                acc1[r] = fmaf(fmaxf(zv + zj1, 0.f), w, acc1[r]);
            }
        }
    }

#pragma unroll
    for (int r = 0; r < 4; ++r) {
        const int irow = i0 + r;
        if (j0 == irow) acc0[r] = NEG_BIG;
        if (j1 == irow) acc1[r] = NEG_BIG;
    }

    float wmax[4];
#pragma unroll
    for (int r = 0; r < 4; ++r) {
        float m = fmaxf(acc0[r], acc1[r]);
#pragma unroll
        for (int off = 32; off >= 1; off >>= 1) m = fmaxf(m, __shfl_xor(m, off));
        wmax[r] = m;
    }
    if (tj == 0) {
#pragma unroll
        for (int r = 0; r < 4; ++r) red[qu][r] = wmax[r];
    }
    __syncthreads();
    float M[4];
#pragma unroll
    for (int r = 0; r < 4; ++r)
        M[r] = fmaxf(fmaxf(red[0][r], red[1][r]), fmaxf(red[2][r], red[3][r]));
    __syncthreads();   // WAR on red

    float e0[4], e1[4];
#pragma unroll
    for (int r = 0; r < 4; ++r) {
        e0[r] = __expf(acc0[r] - M[r]);
        e1[r] = __expf(acc1[r] - M[r]);
        float s = e0[r] + e1[r];
#pragma unroll
        for (int off = 32; off >= 1; off >>= 1) s += __shfl_xor(s, off);
        if (tj == 0) red[qu][r] = s;
    }
    __syncthreads();
#pragma unroll
    for (int r = 0; r < 4; ++r) {
        const float inv = 1.0f / (red[0][r] + red[1][r] + red[2][r] + red[3][r]);
        float* arow = adj + ((size_t)(b * NN + i0 + r)) * NN;
        arow[j0] = e0[r] * inv;
        arow[j1] = e1[r] * inv;
    }
}

// ---------------------------------------------------------------------------
// layer (msg + GRU fused): m = adj@h; mm = relu(m@Wmsg+b); gates; GRU.
// grid 256 x 256: block = (b, 16 rows); wave qu owns rows i0+4qu..+3,
// lane hh owns column.  KEY: 4 rows/wave -> every h / weight value loaded
// into a VGPR feeds 4 FMAs (R4 had 1 row/wave = zero register reuse ->
// ~1 GB L2 traffic; this cuts it 4x and L1-shares the rest).
// adj rows via wave-uniform s_loads; broadcasts via v_readlane.  No LDS.
// ---------------------------------------------------------------------------
__global__ __launch_bounds__(256) void layer_kernel(
    const float* __restrict__ adjw, const float* __restrict__ h_in,
    const float* __restrict__ Wmsg, const float* __restrict__ bmsg,
    const float* __restrict__ Wih, const float* __restrict__ bih,
    const float* __restrict__ Whh, const float* __restrict__ bhh,
    float* __restrict__ h_out)
{
    const int b = blockIdx.x >> 5;                 // 32 tiles per batch
    const int i0 = (blockIdx.x & 31) << 4;         // 16 rows per block
    const int t = threadIdx.x;
    const int hh = t & 63;
    const int qu = __builtin_amdgcn_readfirstlane(t >> 6);
    const int gR = b * NN + i0 + qu * 4;           // first of 4 rows

    float hv[4];
#pragma unroll
    for (int r = 0; r < 4; ++r) hv[r] = h_in[(gR + r) * HH + hh];

    const float* arow = adjw + (size_t)gR * NN;    // wave-uniform -> s_load
    const float* hb = h_in + (size_t)b * NN * HH;

    // phase A: m = adj @ h ; 4 h-values in flight, each feeds 4 rows
    float mac[4] = {0.f, 0.f, 0.f, 0.f};
#pragma unroll 2
    for (int j = 0; j < NN; j += 4) {
        const float h0 = hb[(j + 0) * HH + hh];
        const float h1 = hb[(j + 1) * HH + hh];
        const float h2 = hb[(j + 2) * HH + hh];
        const float h3 = hb[(j + 3) * HH + hh];
#pragma unroll
        for (int r = 0; r < 4; ++r) {
            const float* ar = arow + (size_t)r * NN;
            float a = fmaf(ar[j], h0, mac[r]);
            a = fmaf(ar[j + 1], h1, a);
            a = fmaf(ar[j + 2], h2, a);
            mac[r] = fmaf(ar[j + 3], h3, a);
        }
    }

    // phase B: mm = relu(m @ Wmsg + bmsg) ; one weight load feeds 4 rows
    float mm[4];
#pragma unroll
    for (int r = 0; r < 4; ++r) mm[r] = bmsg[hh];
#pragma unroll 4
    for (int k = 0; k < HH; ++k) {
        const float w = Wmsg[k * HH + hh];
#pragma unroll
        for (int r = 0; r < 4; ++r)
            mm[r] = fmaf(lane_bcast(mac[r], k), w, mm[r]);
    }
#pragma unroll
    for (int r = 0; r < 4; ++r) mm[r] = fmaxf(mm[r], 0.f);

    // phase C: GRU gates ; 6 weight loads feed 24 FMAs
    float g0[4], g1[4], g2[4], g3[4], g4[4], g5[4];
#pragma unroll
    for (int r = 0; r < 4; ++r) {
        g0[r] = bih[hh]; g1[r] = bih[64 + hh]; g2[r] = bih[128 + hh];
        g3[r] = bhh[hh]; g4[r] = bhh[64 + hh]; g5[r] = bhh[128 + hh];
    }
#pragma unroll 2
    for (int k = 0; k < HH; ++k) {
        const float* wi = Wih + k * 192;
        const float* wh = Whh + k * 192;
        const float wi0 = wi[hh], wi1 = wi[64 + hh], wi2 = wi[128 + hh];
        const float wh0 = wh[hh], wh1 = wh[64 + hh], wh2 = wh[128 + hh];
#pragma unroll
        for (int r = 0; r < 4; ++r) {
            const float mv = lane_bcast(mm[r], k);
            const float hk = lane_bcast(hv[r], k);
            g0[r] = fmaf(mv, wi0, g0[r]);
            g1[r] = fmaf(mv, wi1, g1[r]);
            g2[r] = fmaf(mv, wi2, g2[r]);
            g3[r] = fmaf(hk, wh0, g3[r]);
            g4[r] = fmaf(hk, wh1, g4[r]);
            g5[r] = fmaf(hk, wh2, g5[r]);
        }
    }

#pragma unroll
    for (int r = 0; r < 4; ++r) {
        const float rr = 1.f / (1.f + __expf(-(g0[r] + g3[r])));
        const float zz = 1.f / (1.f + __expf(-(g1[r] + g4[r])));
        const float nnv = tanhf(g2[r] + rr * g5[r]);
        h_out[(size_t)(gR + r) * HH + hh] = (1.f - zz) * nnv + zz * hv[r];
    }
}

// ---------------------------------------------------------------------------
// readout: out[b] = mean_i(h[b,i,:]) @ W_out + b_out.  8 blocks x 1024 thr.
// ---------------------------------------------------------------------------
__global__ __launch_bounds__(1024) void readout_kernel(
    const float* __restrict__ h, const float* __restrict__ W_out,
    const float* __restrict__ b_out, float* __restrict__ out)
{
    const int b = blockIdx.x;
    const int t = threadIdx.x;
    const int hh = t & 63;
    const int w = t >> 6;                 // 0..15
    __shared__ float red[16][65];

    float s = 0.f;
#pragma unroll 4
    for (int i = w; i < NN; i += 16) s += h[((size_t)(b * NN + i)) * HH + hh];
    red[w][hh] = s;
    __syncthreads();
    if (w == 0) {
        float tot = 0.f;
#pragma unroll
        for (int r = 0; r < 16; ++r) tot += red[r][hh];
        float v = tot * (1.0f / NN) * W_out[hh];
#pragma unroll
        for (int off = 32; off >= 1; off >>= 1) v += __shfl_xor(v, off);
        if (hh == 0) out[b] = v + b_out[0];
    }
}

extern "C" void kernel_launch(void* const* d_in, const int* in_sizes, int n_in,
                              void* d_out, int out_size, void* d_ws, size_t ws_size,
                              hipStream_t stream)
{
    const float* x     = (const float*)d_in[0];
    const float* W_enc = (const float*)d_in[1];
    const float* b_enc = (const float*)d_in[2];
    const float* W_e1  = (const float*)d_in[3];
    const float* b_e1  = (const float*)d_in[4];
    const float* W_e2  = (const float*)d_in[5];
    const float* b_e2  = (const float*)d_in[6];
    const float* W_msg = (const float*)d_in[7];
    const float* b_msg = (const float*)d_in[8];
    const float* W_ih  = (const float*)d_in[9];
    const float* b_ih  = (const float*)d_in[10];
    const float* W_hh  = (const float*)d_in[11];
    const float* b_hh  = (const float*)d_in[12];
    const float* W_out = (const float*)d_in[13];
    const float* b_out = (const float*)d_in[14];
    float* out = (float*)d_out;

    float* ws  = (float*)d_ws;
    float* h0  = ws;
    float* h1  = h0 + BB * NN * HH;
    float* zi  = h1 + BB * NN * HH;
    float* zj  = zi + BB * NN * HH;
    float* adjw = zj + BB * NN * HH;

    encode_kernel<<<BB * NN / 4, 256, 0, stream>>>(x, W_enc, b_enc, W_e1, b_e1, h0, zi, zj);
    adj_kernel<<<BB * (NN / 4), 256, 0, stream>>>(zi, zj, W_e2, b_e2, adjw);

    layer_kernel<<<BB * (NN / 16), 256, 0, stream>>>(
        adjw, h0, W_msg, b_msg, W_ih, b_ih, W_hh, b_hh, h1);
    layer_kernel<<<BB * (NN / 16), 256, 0, stream>>>(
        adjw, h1, W_msg + HH * HH, b_msg + HH,
        W_ih + HH * 3 * HH, b_ih + 3 * HH, W_hh + HH * 3 * HH, b_hh + 3 * HH, h0);

    readout_kernel<<<BB, 1024, 0, stream>>>(h0, W_out, b_out, out);
}

// Round 7
// 82.770 us; speedup vs baseline: 1.5003x; 1.5003x over previous
//
#include <hip/hip_runtime.h>
#include <math.h>

#define BB 8
#define NN 512
#define FF 32
#define HH 64
#define NEG_BIG (-1.0e30f)

__device__ __forceinline__ float lane_bcast(float v, int l) {
    return __int_as_float(__builtin_amdgcn_readlane(__float_as_int(v), l));
}

// ---------------------------------------------------------------------------
// encode: h = relu(x@W_enc+b); zi = h@W_e1[:H]+b_e1 (folded); zj = h@W_e1[H:]
// grid 1024 x 256: block = 4 rows, wave qu owns row, lane hh owns column.
// ---------------------------------------------------------------------------
__global__ __launch_bounds__(256) void encode_kernel(
    const float* __restrict__ x, const float* __restrict__ W_enc,
    const float* __restrict__ b_enc, const float* __restrict__ W_e1,
    const float* __restrict__ b_e1,
    float* __restrict__ h, float* __restrict__ zi, float* __restrict__ zj)
{
    const int t = threadIdx.x;
    const int hh = t & 63;
    const int qu = __builtin_amdgcn_readfirstlane(t >> 6);
    const int gR = blockIdx.x * 4 + qu;           // 0..B*N-1

    const float* xrow = x + gR * FF;              // wave-uniform -> s_load
    float acc = b_enc[hh];
#pragma unroll
    for (int k = 0; k < FF; ++k)
        acc = fmaf(xrow[k], W_enc[k * HH + hh], acc);
    const float hval = fmaxf(acc, 0.f);
    h[gR * HH + hh] = hval;

    float z1 = b_e1[hh], z2 = 0.f;
#pragma unroll 8
    for (int k = 0; k < HH; ++k) {
        const float hk = lane_bcast(hval, k);
        z1 = fmaf(hk, W_e1[k * HH + hh], z1);
        z2 = fmaf(hk, W_e1[(HH + k) * HH + hh], z2);
    }
    zi[gR * HH + hh] = z1;
    zj[gR * HH + hh] = z2;
}

// ---------------------------------------------------------------------------
// adj: logits[i,j] = sum_k relu(zi[i,k]+zj[j,k])*W_e2[k]+b_e2, diag -inf,
// softmax over j.  grid 1024 x 256: block = (b, 4 rows); wave qu owns
// j-quarter, lane tj handles j0=128qu+tj, j1=j0+64 for all 4 rows.
// zjs[512][17]: lane stride 17 -> conflict-free.
// ---------------------------------------------------------------------------
__global__ __launch_bounds__(256) void adj_kernel(
    const float* __restrict__ zi, const float* __restrict__ zj,
    const float* __restrict__ W_e2, const float* __restrict__ b_e2,
    float* __restrict__ adj)
{
    const int b = blockIdx.x >> 7;
    const int i0 = (blockIdx.x & 127) << 2;
    const int t = threadIdx.x;
    const int qu = __builtin_amdgcn_readfirstlane(t >> 6);
    const int tj = t & 63;
    const int j0 = (qu << 7) + tj;
    const int j1 = j0 + 64;

    __shared__ float zjs[NN][17];
    __shared__ float red[4][8];

    const float be2 = b_e2[0];
    float acc0[4], acc1[4];
#pragma unroll
    for (int r = 0; r < 4; ++r) { acc0[r] = be2; acc1[r] = be2; }

    const float* zib = zi + (b * NN + i0) * HH;   // wave-uniform -> s_load

    for (int kp = 0; kp < 4; ++kp) {
        __syncthreads();
        for (int idx = t; idx < NN * 16; idx += 256) {
            const int row = idx >> 4, c = idx & 15;
            zjs[row][c] = zj[(b * NN + row) * HH + (kp << 4) + c];
        }
        __syncthreads();
#pragma unroll
        for (int c = 0; c < 16; ++c) {
            const int k = (kp << 4) + c;
            const float w = W_e2[k];
            const float zj0 = zjs[j0][c];
            const float zj1 = zjs[j1][c];
#pragma unroll
            for (int r = 0; r < 4; ++r) {
                const float zv = zib[r * HH + k];
                acc0[r] = fmaf(fmaxf(zv + zj0, 0.f), w, acc0[r]);
                acc1[r] = fmaf(fmaxf(zv + zj1, 0.f), w, acc1[r]);
            }
        }
    }

#pragma unroll
    for (int r = 0; r < 4; ++r) {
        const int irow = i0 + r;
        if (j0 == irow) acc0[r] = NEG_BIG;
        if (j1 == irow) acc1[r] = NEG_BIG;
    }

    float wmax[4];
#pragma unroll
    for (int r = 0; r < 4; ++r) {
        float m = fmaxf(acc0[r], acc1[r]);
#pragma unroll
        for (int off = 32; off >= 1; off >>= 1) m = fmaxf(m, __shfl_xor(m, off));
        wmax[r] = m;
    }
    if (tj == 0) {
#pragma unroll
        for (int r = 0; r < 4; ++r) red[qu][r] = wmax[r];
    }
    __syncthreads();
    float M[4];
#pragma unroll
    for (int r = 0; r < 4; ++r)
        M[r] = fmaxf(fmaxf(red[0][r], red[1][r]), fmaxf(red[2][r], red[3][r]));
    __syncthreads();   // WAR on red

    float e0[4], e1[4];
#pragma unroll
    for (int r = 0; r < 4; ++r) {
        e0[r] = __expf(acc0[r] - M[r]);
        e1[r] = __expf(acc1[r] - M[r]);
        float s = e0[r] + e1[r];
#pragma unroll
        for (int off = 32; off >= 1; off >>= 1) s += __shfl_xor(s, off);
        if (tj == 0) red[qu][r] = s;
    }
    __syncthreads();
#pragma unroll
    for (int r = 0; r < 4; ++r) {
        const float inv = 1.0f / (red[0][r] + red[1][r] + red[2][r] + red[3][r]);
        float* arow = adj + ((size_t)(b * NN + i0 + r)) * NN;
        arow[j0] = e0[r] * inv;
        arow[j1] = e1[r] * inv;
    }
}

// ---------------------------------------------------------------------------
// layer (msg + GRU fused).  grid 256 x 1024 (16 waves): block = (b, 16 rows),
// one block per CU, 16 waves/CU.
//  phase A: m = adj@h.  wave = (rg, kc): rows rg*8..+8, j in [64kc, 64kc+64).
//           8 rows/wave -> each h vector load feeds 8 FMAs; 16 waves keep
//           ~128 loads in flight (R6 failure was 4 waves/CU + L2 latency).
//           Partials -> LDS red[kc][row][hh], reduced per-row by wave w.
//  phase B: mm = relu(m@Wmsg+b).  wave w owns row w, full K=64 in-wave.
//  phase C: gates.  wave = (half, rp): half 0 computes gi for rows 2rp..+1
//           from mm, half 1 computes gh from h.  No k-split -> no partials;
//           gbuf overlays dead red (union).
//  finalize: wave w row w: GRU nonlinearity + store.
// ---------------------------------------------------------------------------
__global__ __launch_bounds__(1024) void layer_kernel(
    const float* __restrict__ adjw, const float* __restrict__ h_in,
    const float* __restrict__ Wmsg, const float* __restrict__ bmsg,
    const float* __restrict__ Wih, const float* __restrict__ bih,
    const float* __restrict__ Whh, const float* __restrict__ bhh,
    float* __restrict__ h_out)
{
    const int b  = blockIdx.x >> 5;
    const int i0 = (blockIdx.x & 31) << 4;
    const int t  = threadIdx.x;
    const int hh = t & 63;
    const int w  = __builtin_amdgcn_readfirstlane(t >> 6);   // 0..15
    const int gR0 = b * NN + i0;

    __shared__ union {
        float red[8][16][66];        // phase A partials  [kc][row][hh]
        float gbuf[2][16][3][66];    // phase C gates     [gi/gh][row][gate][hh]
    } U;
    __shared__ float mfull[16][66];
    __shared__ float mmfull[16][66];
    __shared__ float hown[16][66];

    // own 16 rows of h: wave w loads row w (read cross-wave only after barrier)
    hown[w][hh] = h_in[(size_t)(gR0 + w) * HH + hh];

    //=== phase A ==========================================================
    const int rg = w >> 3, kc = w & 7;
    const float* hb = h_in + (size_t)b * NN * HH;
    const float* arow = adjw + (size_t)(gR0 + rg * 8) * NN + kc * 64;
    const float* hj = hb + (size_t)(kc * 64) * HH + hh;

    float mac[8] = {0.f, 0.f, 0.f, 0.f, 0.f, 0.f, 0.f, 0.f};
#pragma unroll 2
    for (int j = 0; j < 64; j += 4) {
        const float h0 = hj[(j + 0) * HH];
        const float h1 = hj[(j + 1) * HH];
        const float h2 = hj[(j + 2) * HH];
        const float h3 = hj[(j + 3) * HH];
#pragma unroll
        for (int r = 0; r < 8; ++r) {
            const float* ar = arow + (size_t)r * NN + j;   // wave-uniform s_load
            mac[r] = fmaf(ar[3], h3,
                     fmaf(ar[2], h2,
                     fmaf(ar[1], h1,
                     fmaf(ar[0], h0, mac[r]))));
        }
    }
#pragma unroll
    for (int r = 0; r < 8; ++r) U.red[kc][rg * 8 + r][hh] = mac[r];
    __syncthreads();

    //=== A-reduce + phase B (wave w owns row w; only own-wave LDS deps) ===
    {
        float s = 0.f;
#pragma unroll
        for (int p = 0; p < 8; ++p) s += U.red[p][w][hh];
        mfull[w][hh] = s;

        float acc = bmsg[hh];
#pragma unroll 4
        for (int k = 0; k < HH; ++k)
            acc = fmaf(mfull[w][k], Wmsg[k * HH + hh], acc);  // broadcast ds + vload
        mmfull[w][hh] = fmaxf(acc, 0.f);
    }
    __syncthreads();

    //=== phase C: 6 gate GEMMs, wave = (half, row-pair) ===================
    const int half = w >> 3, rp = w & 7;
    {
        const float* Wg = half ? Whh : Wih;
        const float* bg = half ? bhh : bih;
        const float (*src)[66] = half ? (const float (*)[66])hown
                                      : (const float (*)[66])mmfull;
        float a0 = bg[hh], a1 = bg[64 + hh], a2 = bg[128 + hh];
        float c0 = a0, c1 = a1, c2 = a2;
#pragma unroll 4
        for (int k = 0; k < HH; ++k) {
            const float* wk = Wg + k * 192;
            const float w0 = wk[hh], w1 = wk[64 + hh], w2 = wk[128 + hh];
            const float va = src[2 * rp][k];      // broadcast ds_read
            const float vb = src[2 * rp + 1][k];
            a0 = fmaf(va, w0, a0); a1 = fmaf(va, w1, a1); a2 = fmaf(va, w2, a2);
            c0 = fmaf(vb, w0, c0); c1 = fmaf(vb, w1, c1); c2 = fmaf(vb, w2, c2);
        }
        U.gbuf[half][2 * rp][0][hh] = a0;
        U.gbuf[half][2 * rp][1][hh] = a1;
        U.gbuf[half][2 * rp][2][hh] = a2;
        U.gbuf[half][2 * rp + 1][0][hh] = c0;
        U.gbuf[half][2 * rp + 1][1][hh] = c1;
        U.gbuf[half][2 * rp + 1][2][hh] = c2;
    }
    __syncthreads();

    //=== finalize: wave w row w ==========================================
    {
        const float ir = U.gbuf[0][w][0][hh], iz = U.gbuf[0][w][1][hh],
                    in = U.gbuf[0][w][2][hh];
        const float hr = U.gbuf[1][w][0][hh], hz = U.gbuf[1][w][1][hh],
                    hn = U.gbuf[1][w][2][hh];
        const float rr = 1.f / (1.f + __expf(-(ir + hr)));
        const float zz = 1.f / (1.f + __expf(-(iz + hz)));
        const float nnv = tanhf(in + rr * hn);
        h_out[(size_t)(gR0 + w) * HH + hh] = (1.f - zz) * nnv + zz * hown[w][hh];
    }
}

// ---------------------------------------------------------------------------
// readout: out[b] = mean_i(h[b,i,:]) @ W_out + b_out.  8 blocks x 1024 thr.
// ---------------------------------------------------------------------------
__global__ __launch_bounds__(1024) void readout_kernel(
    const float* __restrict__ h, const float* __restrict__ W_out,
    const float* __restrict__ b_out, float* __restrict__ out)
{
    const int b = blockIdx.x;
    const int t = threadIdx.x;
    const int hh = t & 63;
    const int w = t >> 6;                 // 0..15
    __shared__ float red[16][65];

    float s = 0.f;
#pragma unroll 4
    for (int i = w; i < NN; i += 16) s += h[((size_t)(b * NN + i)) * HH + hh];
    red[w][hh] = s;
    __syncthreads();
    if (w == 0) {
        float tot = 0.f;
#pragma unroll
        for (int r = 0; r < 16; ++r) tot += red[r][hh];
        float v = tot * (1.0f / NN) * W_out[hh];
#pragma unroll
        for (int off = 32; off >= 1; off >>= 1) v += __shfl_xor(v, off);
        if (hh == 0) out[b] = v + b_out[0];
    }
}

extern "C" void kernel_launch(void* const* d_in, const int* in_sizes, int n_in,
                              void* d_out, int out_size, void* d_ws, size_t ws_size,
                              hipStream_t stream)
{
    const float* x     = (const float*)d_in[0];
    const float* W_enc = (const float*)d_in[1];
    const float* b_enc = (const float*)d_in[2];
    const float* W_e1  = (const float*)d_in[3];
    const float* b_e1  = (const float*)d_in[4];
    const float* W_e2  = (const float*)d_in[5];
    const float* b_e2  = (const float*)d_in[6];
    const float* W_msg = (const float*)d_in[7];
    const float* b_msg = (const float*)d_in[8];
    const float* W_ih  = (const float*)d_in[9];
    const float* b_ih  = (const float*)d_in[10];
    const float* W_hh  = (const float*)d_in[11];
    const float* b_hh  = (const float*)d_in[12];
    const float* W_out = (const float*)d_in[13];
    const float* b_out = (const float*)d_in[14];
    float* out = (float*)d_out;

    float* ws  = (float*)d_ws;
    float* h0  = ws;
    float* h1  = h0 + BB * NN * HH;
    float* zi  = h1 + BB * NN * HH;
    float* zj  = zi + BB * NN * HH;
    float* adjw = zj + BB * NN * HH;

    encode_kernel<<<BB * NN / 4, 256, 0, stream>>>(x, W_enc, b_enc, W_e1, b_e1, h0, zi, zj);
    adj_kernel<<<BB * (NN / 4), 256, 0, stream>>>(zi, zj, W_e2, b_e2, adjw);

    layer_kernel<<<BB * (NN / 16), 1024, 0, stream>>>(
        adjw, h0, W_msg, b_msg, W_ih, b_ih, W_hh, b_hh, h1);
    layer_kernel<<<BB * (NN / 16), 1024, 0, stream>>>(
        adjw, h1, W_msg + HH * HH, b_msg + HH,
        W_ih + HH * 3 * HH, b_ih + 3 * HH, W_hh + HH * 3 * HH, b_hh + 3 * HH, h0);

    readout_kernel<<<BB, 1024, 0, stream>>>(h0, W_out, b_out, out);
}